// Round 11
// baseline (899.618 us; speedup 1.0000x reference)
//
#include <hip/hip_runtime.h>

// PWC-Net correlation (md=4, 81 disps) + leaky_relu(0.1), mean over C=256.
// B=8 C=256 H=96 W=128, f32 in/out.
//
// R11 = R7 (best, 126us) + TRUE T14 async split:
//   LOADREG(cc+1) -> regs; COMPUTE(buf); PACKWRITE(buf^1); sync
// The vmcnt wait for the next chunk's loads lands AFTER compute (R5/R9/
// R10 lesson: any structure where packs immediately follow loads drains
// vmcnt at issue point and hides nothing). One barrier per chunk.
// Block = 3 waves (192 thr), wave = one dy of 3-dy group; grid =
// 8(batch==XCD) x 48(h-tiles) x 3(dy-groups) = 1152 blocks.
// 40 VGPR held across COMPUTE (pa/pb) -> demand ~125; waves_per_eu(3,8)
// caps allocator at 168 so it neither squeezes nor balloons (R8 showed
// 192-thr blocks follow demand; R5/R6's "pinned 84" was 576-thr only).
// Spill sentinel: WRITE_SIZE >> 31MB. R8 lesson: x1 stays LDS-shared.
// f16-pair packing, v_dot2_f32_f16, conflict-free XOR swizzle for b128.

#define B_ 8
#define C_ 256
#define H_ 96
#define W_ 128
#define TH 2
#define CC 8
#define NCH (C_ / CC)            // 32 chunks
#define HW (H_ * W_)
#define CHSTRIDE (CC * HW)       // floats, fits u32
#define S2SZ (4 * 544)           // 2176 u32 (4 staged x2 rows)
#define S1SZ (TH * 512)          // 1024 u32
#define SMSZ (S2SZ + S1SZ)       // 3200 u32 = 12.8 KB per buffer
#define NTHR 192
#define NTASK 800                // 256 x1 + 544 x2 float4-pair tasks
#define NR 5                     // staging rounds: 192*5 >= 800

typedef __fp16 h2_t __attribute__((ext_vector_type(2)));
union H2U { unsigned int u; h2_t h; };

__device__ __forceinline__ h2_t u_as_h2(unsigned int u) { H2U x; x.u = u; return x.h; }

__device__ __forceinline__ unsigned int packh2(float a, float b) {
    H2U x; x.h = __builtin_amdgcn_cvt_pkrtz(a, b); return x.u;
}

#if __has_builtin(__builtin_amdgcn_fdot2)
__device__ __forceinline__ float dot2(unsigned int a, unsigned int b, float c) {
    return __builtin_amdgcn_fdot2(u_as_h2(a), u_as_h2(b), c, false);
}
#else
__device__ __forceinline__ float dot2(unsigned int a, unsigned int b, float c) {
    h2_t ha = u_as_h2(a), hb = u_as_h2(b);
    return c + (float)ha[0] * (float)hb[0] + (float)ha[1] * (float)hb[1];
}
#endif

__global__ __attribute__((amdgpu_flat_work_group_size(NTHR, NTHR)))
__attribute__((amdgpu_waves_per_eu(3, 8)))
void corr_kernel(const float* __restrict__ x1, const float* __restrict__ x2,
                 float* __restrict__ out)
{
    // per buffer: s2 (4 rows x 544) at [0, S2SZ), s1 (2 rows x 512) after
    __shared__ __align__(16) unsigned int smem[2][SMSZ];   // 25.6 KB

    const int b   = blockIdx.x;       // batch == XCD (x fastest => round-robin)
    const int h0  = blockIdx.y * TH;
    const int dg  = blockIdx.z;       // dy = 3*dg + wid
    const int tid = threadIdx.x;
    const int wid = tid >> 6;         // 0..2
    const int lane = tid & 63;
    const int hr  = lane >> 5;        // 0..1
    const int wq  = lane & 31;        // 32 groups of 4 w pixels

    // ---------------- staging descriptors (5 rounds x 192 threads) ---------
    // task u<256: x1. cp=u&3, w4=(u>>2)&31, rx=u>>7.
    // task 256<=u<800: x2. v=u-256: cp=v&3, q=v>>2, g=q%34 (0..33), r=q/34.
    // LDS slot for pixel-slot s, ch-pair cp, row r:
    //   r*544(or 512) + (s>>3)*32 + (((s&7)^((s>>3)&7)^(r&7))<<2) + cp
    // task covers s=4g..4g+3 -> idx_k = c + ((k^X)<<2).
    unsigned off_[NR];
    int cx_[NR];                       // c | (X<<16)
    int mval = 0, msrc = 0;            // valid / source-is-x2 bitmasks
    #pragma unroll
    for (int r5 = 0; r5 < NR; ++r5) {
        const int u = tid + NTHR * r5;
        unsigned off = 0; int c = 0, X = 0; bool val = false, src2 = false;
        if (u < 256) {
            const int cp = u & 3, w4 = (u >> 2) & 31, rx = u >> 7;
            off = ((unsigned)(b * C_ + 2 * cp) * H_ + (unsigned)(h0 + rx)) * W_
                + (unsigned)(4 * w4);
            c = S2SZ + rx * 512 + (w4 >> 1) * 32 + cp;
            X = (4 * (w4 & 1)) ^ ((w4 >> 1) & 7) ^ rx;
            val = true;
        } else if (u < NTASK) {
            const int v = u - 256;
            const int cp = v & 3, q = v >> 2;
            const int g = q % 34, r = q / 34;
            const int h2 = h0 + 3 * dg + r - 4;
            val = (h2 >= 0) && (h2 < H_) && (g >= 1) && (g <= 32);
            const int h2c = val ? h2 : 0, gc = val ? g : 1;
            off = ((unsigned)(b * C_ + 2 * cp) * H_ + (unsigned)h2c) * W_
                + (unsigned)(4 * gc - 4);
            c = r * 544 + (g >> 1) * 32 + cp;
            X = (4 * (g & 1)) ^ ((g >> 1) & 7) ^ (r & 7);
            src2 = true;
        }
        off_[r5] = off;
        cx_[r5]  = c | (X << 16);
        mval |= (int)val << r5;
        msrc |= (int)src2 << r5;
    }

    // prefetch registers: held across COMPUTE (the T14 state)
    float4 pa[NR], pb[NR];

    auto LOADREG = [&](int cc) {
        const unsigned co = (unsigned)cc * (unsigned)CHSTRIDE;
        #pragma unroll
        for (int r5 = 0; r5 < NR; ++r5) {
            if ((mval >> r5) & 1) {
                const float* base = ((msrc >> r5) & 1) ? x2 : x1;
                pa[r5] = *reinterpret_cast<const float4*>(base + off_[r5] + co);
                pb[r5] = *reinterpret_cast<const float4*>(base + off_[r5] + co + HW);
            }
        }
    };
    auto PACKWRITE = [&](unsigned int* SM) {
        #pragma unroll
        for (int r5 = 0; r5 < NR; ++r5) {
            if ((mval >> r5) & 1) {
                const int c = cx_[r5] & 0xffff;
                const int X = cx_[r5] >> 16;
                SM[c + ((0 ^ X) << 2)] = packh2(pa[r5].x, pb[r5].x);
                SM[c + ((1 ^ X) << 2)] = packh2(pa[r5].y, pb[r5].y);
                SM[c + ((2 ^ X) << 2)] = packh2(pa[r5].z, pb[r5].z);
                SM[c + ((3 ^ X) << 2)] = packh2(pa[r5].w, pb[r5].w);
            }
        }
    };

    // ---------------- compute setup (R7 verbatim) ----------------
    const int base1 = S2SZ + hr * 512 + (wq >> 1) * 32;
    const int S1X   = (4 * (wq & 1)) ^ ((wq >> 1) & 7) ^ hr;
    const int row   = hr + wid;            // staged x2 row 0..3

    int a2[12];                            // chunk-invariant x2 read addresses
    #pragma unroll
    for (int t = 0; t < 12; ++t) {
        const int sp = 4 * wq + t;         // padded pixel index 0..135
        a2[t] = row * 544 + (sp >> 3) * 32
              + (((sp & 7) ^ ((sp >> 3) & 7) ^ row) << 2);
    }

    float acc[4][9];
    #pragma unroll
    for (int p = 0; p < 4; ++p)
        #pragma unroll
        for (int d = 0; d < 9; ++d) acc[p][d] = 0.f;

    auto COMPUTE = [&](const unsigned int* SM) {
        uint4 x1v[4];
        #pragma unroll
        for (int p = 0; p < 4; ++p)
            x1v[p] = *reinterpret_cast<const uint4*>(&SM[base1 + ((p ^ S1X) << 2)]);
        #pragma unroll
        for (int t = 0; t < 12; ++t) {
            const uint4 x2v = *reinterpret_cast<const uint4*>(&SM[a2[t]]);
            #pragma unroll
            for (int p = 0; p < 4; ++p) {
                const int dxx = t - p;          // compile-time after unroll
                if (dxx >= 0 && dxx <= 8) {
                    float a = acc[p][dxx];
                    a = dot2(x1v[p].x, x2v.x, a);
                    a = dot2(x1v[p].y, x2v.y, a);
                    a = dot2(x1v[p].z, x2v.z, a);
                    a = dot2(x1v[p].w, x2v.w, a);
                    acc[p][dxx] = a;
                }
            }
        }
    };

    // ---------------- chunk loop: T14 split, ONE barrier per chunk ---------
    // zero pad slots of both buffers (never rewritten by staging)
    for (int i = tid; i < 2 * SMSZ; i += NTHR) (&smem[0][0])[i] = 0u;
    LOADREG(0);
    __syncthreads();                  // zeros visible before first write
    PACKWRITE(&smem[0][0]);
    __syncthreads();                  // buf0 ready (chunk 0)

    unsigned int* const S0 = &smem[0][0];
    unsigned int* const S1 = &smem[1][0];

    #pragma unroll 1
    for (int cc = 0; cc < NCH - 2; cc += 2) {
        LOADREG(cc + 1);              // issue loads
        COMPUTE(S0);                  // chunk cc   (hides load latency)
        PACKWRITE(S1);                // vmcnt wait lands here
        __syncthreads();              // buf1 ready / buf0 free
        LOADREG(cc + 2);
        COMPUTE(S1);                  // chunk cc+1
        PACKWRITE(S0);
        __syncthreads();              // buf0 ready / buf1 free
    }
    LOADREG(NCH - 1);
    COMPUTE(S0);                      // chunk 30
    PACKWRITE(S1);
    __syncthreads();
    COMPUTE(S1);                      // chunk 31

    // ---------------- epilogue: mean + leaky_relu + coalesced f32x4 writes -
    const float inv = 1.0f / 256.0f;
    const int dy = 3 * dg + wid;
    float* ob = out + (((size_t)(b * 81 + dy * 9)) * H_ + (h0 + hr)) * W_ + wq * 4;
    #pragma unroll
    for (int dxx = 0; dxx < 9; ++dxx) {
        float4 o;
        float v;
        v = acc[0][dxx] * inv; o.x = v >= 0.f ? v : 0.1f * v;
        v = acc[1][dxx] * inv; o.y = v >= 0.f ? v : 0.1f * v;
        v = acc[2][dxx] * inv; o.z = v >= 0.f ? v : 0.1f * v;
        v = acc[3][dxx] * inv; o.w = v >= 0.f ? v : 0.1f * v;
        *reinterpret_cast<float4*>(ob + (size_t)dxx * HW) = o;
    }
}

extern "C" void kernel_launch(void* const* d_in, const int* in_sizes, int n_in,
                              void* d_out, int out_size, void* d_ws, size_t ws_size,
                              hipStream_t stream) {
    const float* x1 = (const float*)d_in[0];
    const float* x2 = (const float*)d_in[1];
    float* out = (float*)d_out;
    corr_kernel<<<dim3(B_, H_ / TH, 3), dim3(NTHR), 0, stream>>>(x1, x2, out);
}

// Round 12
// 82.323 us; speedup vs baseline: 10.9279x; 10.9279x over previous
//
#include <hip/hip_runtime.h>

// PWC-Net correlation (md=4, 81 disps) + leaky_relu(0.1), mean over C=256.
// B=8 C=256 H=96 W=128, f32 in/out.
//
// R12 = R7 (best, 126us) with WIDE STAGING TASKS:
//   one thread = one slot-quad x ALL 4 ch-pairs: 8 coalesced float4 loads
//   -> 16 packh2 -> 4 x ds_write_b128  (R7: 4 strided ds_write_b32/task).
//   LDS write ops per block-chunk: 3200 b32 -> 768 b128 (same bytes, ~2x
//   fewer write cycles); staging addr-VALU ~2x fewer insts; exactly 192
//   valid tasks = one per thread (pad quads pre-zeroed, never staged).
// Compute / swizzle / layout / loop structure: R7 verbatim.
// Block = 3 waves (192 thr), wave = one dy of 3-dy group; grid =
// 8(batch==XCD) x 48(h-tiles) x 3(dy-groups) = 1152 blocks.
// Lessons: allocator pins ~84 VGPR for this kernel (R5/R6/R11 -- attrs
// don't move it; holding state across COMPUTE spills, 900us). Keep all
// staging live ranges short. Spill sentinel: WRITE_SIZE >> 31MB.
// R8: x1 stays LDS-shared. R9/R10/R11: don't reorder phases, cheapen them.

#define B_ 8
#define C_ 256
#define H_ 96
#define W_ 128
#define TH 2
#define CC 8
#define NCH (C_ / CC)            // 32 chunks
#define HW (H_ * W_)
#define CHSTRIDE (CC * HW)       // floats, fits u32
#define S2SZ (4 * 544)           // 2176 u32 (4 staged x2 rows)
#define S1SZ (TH * 512)          // 1024 u32
#define SMSZ (S2SZ + S1SZ)       // 3200 u32 = 12.8 KB
#define NTHR 192

typedef __fp16 h2_t __attribute__((ext_vector_type(2)));
union H2U { unsigned int u; h2_t h; };

__device__ __forceinline__ h2_t u_as_h2(unsigned int u) { H2U x; x.u = u; return x.h; }

__device__ __forceinline__ unsigned int packh2(float a, float b) {
    H2U x; x.h = __builtin_amdgcn_cvt_pkrtz(a, b); return x.u;
}

#if __has_builtin(__builtin_amdgcn_fdot2)
__device__ __forceinline__ float dot2(unsigned int a, unsigned int b, float c) {
    return __builtin_amdgcn_fdot2(u_as_h2(a), u_as_h2(b), c, false);
}
#else
__device__ __forceinline__ float dot2(unsigned int a, unsigned int b, float c) {
    h2_t ha = u_as_h2(a), hb = u_as_h2(b);
    return c + (float)ha[0] * (float)hb[0] + (float)ha[1] * (float)hb[1];
}
#endif

__global__ __attribute__((amdgpu_flat_work_group_size(NTHR, NTHR)))
void corr_kernel(const float* __restrict__ x1, const float* __restrict__ x2,
                 float* __restrict__ out)
{
    // s2 (4 rows x 544) at [0, S2SZ), s1 (2 rows x 512) at [S2SZ, SMSZ)
    __shared__ __align__(16) unsigned int smem[SMSZ];

    const int b   = blockIdx.x;       // batch == XCD (x fastest => round-robin)
    const int h0  = blockIdx.y * TH;
    const int dg  = blockIdx.z;       // dy = 3*dg + wid
    const int tid = threadIdx.x;
    const int wid = tid >> 6;         // 0..2
    const int lane = tid & 63;
    const int hr  = lane >> 5;        // 0..1
    const int wq  = lane & 31;        // 32 groups of 4 w pixels

    // ---------------- staging descriptor: ONE wide task per thread ---------
    // tid<64: x1 task. rx=tid>>5, w4=tid&31. Covers pixels 4w4..4w4+3,
    //   channels 0..7 of the chunk (4 ch-pairs).
    // tid>=64: x2 task. v=tid-64: r=v>>5, g=(v&31)+1 (g=1..32; pad quads
    //   g=0/33 pre-zeroed, never staged). Covers padded slots 4g..4g+3.
    // LDS u32 idx for slot s, ch-pair cp, row r:
    //   [S2SZ +] r*544(512) + (s>>3)*32 + (((s&7)^((s>>3)&7)^(r&7))<<2) + cp
    // One uint4 write covers cp 0..3 of one swizzled slot: addr c+((k^X)<<2).
    unsigned off; int c, X; bool val, src2;
    if (tid < 64) {
        const int rx = tid >> 5, w4 = tid & 31;
        off = ((unsigned)(b * C_) * H_ + (unsigned)(h0 + rx)) * W_ + 4u * w4;
        c = S2SZ + rx * 512 + (w4 >> 1) * 32;
        X = (4 * (w4 & 1)) ^ ((w4 >> 1) & 7) ^ rx;
        val = true; src2 = false;
    } else {
        const int v = tid - 64;
        const int r = v >> 5, g = (v & 31) + 1;
        const int h2 = h0 + 3 * dg + r - 4;
        val = (h2 >= 0) && (h2 < H_);
        const int h2c = val ? h2 : 0;
        off = ((unsigned)(b * C_) * H_ + (unsigned)h2c) * W_ + (unsigned)(4 * g - 4);
        c = r * 544 + (g >> 1) * 32;
        X = (4 * (g & 1)) ^ ((g >> 1) & 7) ^ (r & 7);
        src2 = true;
    }
    const float* const sbase = src2 ? x2 : x1;

    auto STAGE = [&](int cc) {
        if (val) {
            const float* p = sbase + off + (unsigned)cc * (unsigned)CHSTRIDE;
            const float4 A0 = *reinterpret_cast<const float4*>(p);
            const float4 B0 = *reinterpret_cast<const float4*>(p + HW);
            const float4 A1 = *reinterpret_cast<const float4*>(p + 2 * HW);
            const float4 B1 = *reinterpret_cast<const float4*>(p + 3 * HW);
            const float4 A2 = *reinterpret_cast<const float4*>(p + 4 * HW);
            const float4 B2 = *reinterpret_cast<const float4*>(p + 5 * HW);
            const float4 A3 = *reinterpret_cast<const float4*>(p + 6 * HW);
            const float4 B3 = *reinterpret_cast<const float4*>(p + 7 * HW);
            uint4 w0, w1, w2, w3;   // pixel k -> {cp0,cp1,cp2,cp3}
            w0.x = packh2(A0.x, B0.x); w0.y = packh2(A1.x, B1.x);
            w0.z = packh2(A2.x, B2.x); w0.w = packh2(A3.x, B3.x);
            w1.x = packh2(A0.y, B0.y); w1.y = packh2(A1.y, B1.y);
            w1.z = packh2(A2.y, B2.y); w1.w = packh2(A3.y, B3.y);
            w2.x = packh2(A0.z, B0.z); w2.y = packh2(A1.z, B1.z);
            w2.z = packh2(A2.z, B2.z); w2.w = packh2(A3.z, B3.z);
            w3.x = packh2(A0.w, B0.w); w3.y = packh2(A1.w, B1.w);
            w3.z = packh2(A2.w, B2.w); w3.w = packh2(A3.w, B3.w);
            *reinterpret_cast<uint4*>(&smem[c + ((0 ^ X) << 2)]) = w0;
            *reinterpret_cast<uint4*>(&smem[c + ((1 ^ X) << 2)]) = w1;
            *reinterpret_cast<uint4*>(&smem[c + ((2 ^ X) << 2)]) = w2;
            *reinterpret_cast<uint4*>(&smem[c + ((3 ^ X) << 2)]) = w3;
        }
    };

    // ---------------- compute setup (R7 verbatim) ----------------
    const int base1 = S2SZ + hr * 512 + (wq >> 1) * 32;
    const int S1X   = (4 * (wq & 1)) ^ ((wq >> 1) & 7) ^ hr;
    const int row   = hr + wid;            // staged x2 row 0..3

    int a2[12];                            // chunk-invariant x2 read addresses
    #pragma unroll
    for (int t = 0; t < 12; ++t) {
        const int sp = 4 * wq + t;         // padded pixel index 0..135
        a2[t] = row * 544 + (sp >> 3) * 32
              + (((sp & 7) ^ ((sp >> 3) & 7) ^ row) << 2);
    }

    float acc[4][9];
    #pragma unroll
    for (int p = 0; p < 4; ++p)
        #pragma unroll
        for (int d = 0; d < 9; ++d) acc[p][d] = 0.f;

    auto COMPUTE = [&]() {
        uint4 x1v[4];
        #pragma unroll
        for (int p = 0; p < 4; ++p)
            x1v[p] = *reinterpret_cast<const uint4*>(&smem[base1 + ((p ^ S1X) << 2)]);
        #pragma unroll
        for (int t = 0; t < 12; ++t) {
            const uint4 x2v = *reinterpret_cast<const uint4*>(&smem[a2[t]]);
            #pragma unroll
            for (int p = 0; p < 4; ++p) {
                const int dxx = t - p;          // compile-time after unroll
                if (dxx >= 0 && dxx <= 8) {
                    float a = acc[p][dxx];
                    a = dot2(x1v[p].x, x2v.x, a);
                    a = dot2(x1v[p].y, x2v.y, a);
                    a = dot2(x1v[p].z, x2v.z, a);
                    a = dot2(x1v[p].w, x2v.w, a);
                    acc[p][dxx] = a;
                }
            }
        }
    };

    // ---------------- chunk loop (R7 structure) ----------------------------
    // zero pad slots of s2 (g=0/33 quads, out-of-range rows; never staged)
    for (int i = tid; i < S2SZ; i += NTHR) smem[i] = 0u;
    __syncthreads();

    #pragma unroll 1
    for (int cc = 0; cc < NCH; ++cc) {
        STAGE(cc);
        __syncthreads();
        COMPUTE();
        __syncthreads();
    }

    // ---------------- epilogue: mean + leaky_relu + coalesced f32x4 writes -
    const float inv = 1.0f / 256.0f;
    const int dy = 3 * dg + wid;
    float* ob = out + (((size_t)(b * 81 + dy * 9)) * H_ + (h0 + hr)) * W_ + wq * 4;
    #pragma unroll
    for (int dxx = 0; dxx < 9; ++dxx) {
        float4 o;
        float v;
        v = acc[0][dxx] * inv; o.x = v >= 0.f ? v : 0.1f * v;
        v = acc[1][dxx] * inv; o.y = v >= 0.f ? v : 0.1f * v;
        v = acc[2][dxx] * inv; o.z = v >= 0.f ? v : 0.1f * v;
        v = acc[3][dxx] * inv; o.w = v >= 0.f ? v : 0.1f * v;
        *reinterpret_cast<float4*>(ob + (size_t)dxx * HW) = o;
    }
}

extern "C" void kernel_launch(void* const* d_in, const int* in_sizes, int n_in,
                              void* d_out, int out_size, void* d_ws, size_t ws_size,
                              hipStream_t stream) {
    const float* x1 = (const float*)d_in[0];
    const float* x2 = (const float*)d_in[1];
    float* out = (float*)d_out;
    corr_kernel<<<dim3(B_, H_ / TH, 3), dim3(NTHR), 0, stream>>>(x1, x2, out);
}